// Round 11
// baseline (810.714 us; speedup 1.0000x reference)
//
#include <hip/hip_runtime.h>
#include <math.h>

typedef unsigned long long ull;

#define NN1 50000
#define EE  600000
#define KK1 25000
#define KK2 12500

#define NB (1<<18)      // rank buckets
#define BSHIFT 46       // 64-18

#define CDIV(a,b) (((a)+(b)-1)/(b))

__device__ __forceinline__ ull encd(double d){
  ull u = (ull)__double_as_longlong(d);
  return (u & 0x8000000000000000ULL) ? ~u : (u | 0x8000000000000000ULL);
}
__device__ __forceinline__ double lrelu(double z){ return z > 0.0 ? z : 0.2*z; }

// ---------------- Q = [W.a_src | W.a_dst | W.p_heads] : [256][12] f64 ; block 256 = pnorm ----
__global__ void prepq_k(const float* __restrict__ W, const float* __restrict__ as,
                        const float* __restrict__ ad, const float* __restrict__ p,
                        const float* __restrict__ bias, double* __restrict__ Q,
                        double* __restrict__ nrmbp){
  int tid = threadIdx.x;
  if (blockIdx.x == 256){
    __shared__ double ws_[8];
    double pv = (double)p[tid];
    double v = pv*pv;
    double w = (double)bias[tid]*pv;
    for (int off=32; off; off>>=1){ v += __shfl_down(v, off); w += __shfl_down(w, off); }
    if ((tid&63)==0){ ws_[tid>>6] = v; ws_[4+(tid>>6)] = w; }
    __syncthreads();
    if (tid == 0){
      nrmbp[0] = sqrt(ws_[0]+ws_[1]+ws_[2]+ws_[3]);
      nrmbp[1] = ws_[4]+ws_[5]+ws_[6]+ws_[7];
    }
    return;
  }
  int k = blockIdx.x; int head = tid>>6; int lane = tid&63;
  double w = (double)W[k*256 + tid];
  double vs = w*(double)as[tid], vd = w*(double)ad[tid], vp = w*(double)p[tid];
  for (int off=32; off; off>>=1){
    vs += __shfl_down(vs,off); vd += __shfl_down(vd,off); vp += __shfl_down(vp,off);
  }
  if (lane==0){ Q[k*12+head]=vs; Q[k*12+4+head]=vd; Q[k*12+8+head]=vp; }
}

// ---------------- matvec: als/ald/hp = A[n,256] @ Q[256,12], f64 ; zeroes deg ----------------
template<typename TA>
__global__ __launch_bounds__(256) void matvec_k(const TA* __restrict__ A, const double* __restrict__ Q,
                                                double* __restrict__ als, double* __restrict__ ald,
                                                double* __restrict__ hp, int* __restrict__ deg, int n){
  __shared__ double P[4][64][13];
  int tid = threadIdx.x;
  int w = tid >> 6, l = tid & 63;
  int base = blockIdx.x*64;
  int r = base + l;
  double acc[12];
  #pragma unroll
  for (int j=0;j<12;j++) acc[j] = 0.0;
  if (r < n){
    const TA*    rowp = A + (size_t)r*256 + w*64;
    const double* qp  = Q + (size_t)w*64*12;
    if constexpr (sizeof(TA)==4){
      #pragma unroll 4
      for (int i=0;i<16;i++){
        float4 v = *reinterpret_cast<const float4*>(rowp + i*4);
        double e0=(double)v.x, e1=(double)v.y, e2=(double)v.z, e3=(double)v.w;
        #pragma unroll
        for (int j=0;j<12;j++) acc[j] = fma(e0, qp[(i*4+0)*12+j], acc[j]);
        #pragma unroll
        for (int j=0;j<12;j++) acc[j] = fma(e1, qp[(i*4+1)*12+j], acc[j]);
        #pragma unroll
        for (int j=0;j<12;j++) acc[j] = fma(e2, qp[(i*4+2)*12+j], acc[j]);
        #pragma unroll
        for (int j=0;j<12;j++) acc[j] = fma(e3, qp[(i*4+3)*12+j], acc[j]);
      }
    } else {
      #pragma unroll 4
      for (int i=0;i<32;i++){
        double2 v = *reinterpret_cast<const double2*>(rowp + i*2);
        #pragma unroll
        for (int j=0;j<12;j++) acc[j] = fma(v.x, qp[(i*2+0)*12+j], acc[j]);
        #pragma unroll
        for (int j=0;j<12;j++) acc[j] = fma(v.y, qp[(i*2+1)*12+j], acc[j]);
      }
    }
  }
  #pragma unroll
  for (int j=0;j<12;j++) P[w][l][j] = acc[j];
  __syncthreads();
  if (tid < 64){
    int rr = base + tid;
    if (rr < n){
      double s[12];
      #pragma unroll
      for (int j=0;j<12;j++)
        s[j] = ((P[0][tid][j] + P[1][tid][j]) + P[2][tid][j]) + P[3][tid][j];
      #pragma unroll
      for (int h=0;h<4;h++){
        als[rr*4+h] = s[h];
        ald[rr*4+h] = s[4+h];
        hp [rr*4+h] = s[8+h];
      }
      deg[rr] = 0;
    }
  }
}

__global__ void deg_k(const int* __restrict__ dst, const int* __restrict__ msk,
                      int* __restrict__ deg, int e){
  int t = blockIdx.x*blockDim.x + threadIdx.x;
  if (t >= e) return;
  if (msk && !msk[t]) return;
  atomicAdd(&deg[dst[t]], 1);
}

// ---------------- hierarchical scan (blocks of 256) ----------------
__global__ __launch_bounds__(256) void scanA_k(int* __restrict__ a, int* __restrict__ btot, int n){
  __shared__ int s[256];
  int g = blockIdx.x*256 + threadIdx.x;
  s[threadIdx.x] = (g < n) ? a[g] : 0;
  __syncthreads();
  for (int off=1; off<256; off<<=1){
    int t = (threadIdx.x >= off) ? s[threadIdx.x-off] : 0;
    __syncthreads();
    s[threadIdx.x] += t;
    __syncthreads();
  }
  if (g < n) a[g] = s[threadIdx.x];
  if (threadIdx.x == 255) btot[blockIdx.x] = s[255];
}

__global__ __launch_bounds__(1024) void scanB_k(int* __restrict__ btot, int nb){
  __shared__ int s[1024];
  int t = threadIdx.x;
  s[t] = (t < nb) ? btot[t] : 0;
  __syncthreads();
  for (int off=1; off<1024; off<<=1){
    int v = (t >= off) ? s[t-off] : 0;
    __syncthreads();
    s[t] += v;
    __syncthreads();
  }
  if (t < nb) btot[t] = s[t];
}

__global__ void scanC_rowptr_k(const int* __restrict__ a, const int* __restrict__ btot,
                               int* __restrict__ rowptr, int* __restrict__ cursor, int n){
  int g = blockIdx.x*blockDim.x + threadIdx.x;
  if (g >= n) return;
  int B = g >> 8;
  int off = (B > 0) ? btot[B-1] : 0;
  rowptr[g+1] = a[g] + off;
  cursor[g] = 0;
  if (g == 0) rowptr[0] = 0;
}

__global__ void scanC_above_k(const int* __restrict__ a, const int* __restrict__ btot,
                              int* __restrict__ habove, int nelems, int nbins){
  int g = blockIdx.x*blockDim.x + threadIdx.x;
  if (g >= nbins) return;
  int B = g >> 8;
  int off = (B > 0) ? btot[B-1] : 0;
  habove[g] = nelems - (a[g] + off);
}

// place src into csr slots of dst; also zero hist/bcur (used later in pooling)
__global__ void place_k(const int* __restrict__ dst, const int* __restrict__ msk,
                        const int* __restrict__ src, const int* __restrict__ rowptr,
                        int* __restrict__ cursor, int* __restrict__ csr,
                        int* __restrict__ hist, int* __restrict__ bcur, int e){
  int t = blockIdx.x*blockDim.x + threadIdx.x;
  if (t < NB){ hist[t] = 0; bcur[t] = 0; }
  if (t >= e) return;
  if (msk && !msk[t]) return;
  int d = dst[t];
  int slot = atomicAdd(&cursor[d], 1);
  csr[rowptr[d] + slot] = src[t];
}

// ---------------- per-node: segment max, softmax weights, pooling score ----------------
__global__ void nodew_k(const double* __restrict__ als, const double* __restrict__ ald,
                        const double* __restrict__ hp, const int* __restrict__ csr,
                        const int* __restrict__ rowptr, const double* __restrict__ nrmbp,
                        double* __restrict__ wse, double* __restrict__ wed,
                        double* __restrict__ z, int n){
  int g = blockIdx.x*blockDim.x + threadIdx.x;
  int i = g>>2, h = g&3;
  if (i >= n) return;
  double aldv = ald[g];
  double selfev = lrelu(als[g] + aldv);
  int b = rowptr[i], e = rowptr[i+1];
  double m = selfev;
  for (int t=b; t<e; t++){
    int s = csr[t];
    double ev = lrelu(als[s*4+h] + aldv);
    m = fmax(m, ev);
  }
  double ws = exp(selfev - m);
  wse[g] = ws;
  double acc = ws * hp[g];
  double den = ws;
  for (int t=b; t<e; t++){
    int s = csr[t];
    double ev = lrelu(als[s*4+h] + aldv);
    double w = exp(ev - m);
    wed[(long)t*4+h] = w;
    acc = fma(w, hp[(long)s*4+h], acc);
    den += w;
  }
  double part = acc/den;
  part += __shfl_xor(part, 1);
  part += __shfl_xor(part, 2);
  if (h == 0) z[i] = (part + nrmbp[1]) / nrmbp[0];
}

// ---------------- per-head aggregation of raw features for kept nodes ----------------
template<typename TA>
__global__ void aggx4_k(const TA* __restrict__ X, const int* __restrict__ prm,
                        const int* __restrict__ rowptr, const int* __restrict__ csr,
                        const double* __restrict__ wed, const double* __restrict__ wse,
                        double* __restrict__ Xagg){
  int r = blockIdx.x, k = threadIdx.x;
  int i = prm[r];
  double w0 = wse[i*4+0], w1 = wse[i*4+1], w2 = wse[i*4+2], w3 = wse[i*4+3];
  double xv = (double)X[(long)i*256 + k];
  double a0=w0*xv, a1=w1*xv, a2=w2*xv, a3=w3*xv;
  double d0=w0, d1=w1, d2=w2, d3=w3;
  int b = rowptr[i], e = rowptr[i+1];
  for (int t=b; t<e; t++){
    int s = csr[t];
    double sv = (double)X[(long)s*256 + k];
    double e0=wed[(long)t*4+0], e1=wed[(long)t*4+1];
    double e2=wed[(long)t*4+2], e3=wed[(long)t*4+3];
    a0=fma(e0,sv,a0); a1=fma(e1,sv,a1); a2=fma(e2,sv,a2); a3=fma(e3,sv,a3);
    d0+=e0; d1+=e1; d2+=e2; d3+=e3;
  }
  long base = (long)r*1024 + k;
  Xagg[base      ] = a0/d0;
  Xagg[base + 256] = a1/d1;
  Xagg[base + 512] = a2/d2;
  Xagg[base + 768] = a3/d3;
}

// ---------------- GEMM + epilogue: Out[r][c] = relu(scs[r]*(Xagg_h@W_h + b)) ----------------
// 32x64 tile (grid ~1564 blocks -> ~6 blocks/CU), 2x4 acc/thread, k ascending (bit-exact).
template<typename TO>
__global__ __launch_bounds__(256) void gemmE_k(const double* __restrict__ A,
                                               const float* __restrict__ W,
                                               const float* __restrict__ bias,
                                               const double* __restrict__ scs,
                                               TO* __restrict__ Out, int n){
  __shared__ double As[32][34];
  __shared__ double Bs[32][68];
  int tid = threadIdx.x;
  int r0 = blockIdx.x*32; int head = blockIdx.y; int c0 = head*64;
  int tr = tid>>4, tc = tid&15;
  double acc[2][4] = {};
  for (int k0=0; k0<256; k0+=32){
    int kA = tid&31, rA = tid>>5;
    #pragma unroll
    for (int i=0;i<4;i++){
      int rr = rA + i*8; int gr = r0+rr;
      As[rr][kA] = (gr<n) ? A[(long)gr*1024 + head*256 + k0 + kA] : 0.0;
    }
    int cB = tid&63, kB = tid>>6;
    #pragma unroll
    for (int i=0;i<8;i++){
      int kk = kB + i*4;
      Bs[kk][cB] = (double)W[(k0+kk)*256 + c0 + cB];
    }
    __syncthreads();
    #pragma unroll 4
    for (int k=0;k<32;k+=2){
      double2 a2[2];
      double blo[4], bhi[4];
      #pragma unroll
      for (int i=0;i<2;i++) a2[i] = *reinterpret_cast<const double2*>(&As[tr*2+i][k]);
      #pragma unroll
      for (int j=0;j<4;j++){ blo[j] = Bs[k][tc+16*j]; bhi[j] = Bs[k+1][tc+16*j]; }
      #pragma unroll
      for (int i=0;i<2;i++)
        #pragma unroll
        for (int j=0;j<4;j++) acc[i][j] = fma(a2[i].x, blo[j], acc[i][j]);
      #pragma unroll
      for (int i=0;i<2;i++)
        #pragma unroll
        for (int j=0;j<4;j++) acc[i][j] = fma(a2[i].y, bhi[j], acc[i][j]);
    }
    __syncthreads();
  }
  #pragma unroll
  for (int i=0;i<2;i++){
    int gr = r0 + tr*2 + i;
    if (gr < n){
      double s = scs[gr];
      #pragma unroll
      for (int j=0;j<4;j++){
        int c = c0 + tc + 16*j;
        double v = (acc[i][j] + (double)bias[c]) * s;
        Out[(long)gr*256 + c] = (TO)(v > 0.0 ? v : 0.0);
      }
    }
  }
}

// ---------------- bucket-based exact ranking ----------------
__global__ void keyhist_k(const double* __restrict__ z, ull* __restrict__ k64,
                          int* __restrict__ hist, int n){
  int i = blockIdx.x*blockDim.x + threadIdx.x;
  if (i >= n) return;
  ull e = encd(z[i]);
  k64[i] = e;
  atomicAdd(&hist[(int)(e >> BSHIFT)], 1);
}

__global__ void bplace_k(const ull* __restrict__ k64, const int* __restrict__ habove,
                         int* __restrict__ cur, int* __restrict__ isort, int n){
  int i = blockIdx.x*blockDim.x + threadIdx.x;
  if (i >= n) return;
  int b = (int)(k64[i] >> BSHIFT);
  int slot = atomicAdd(&cur[b], 1);
  isort[habove[b] + slot] = i;
}

// rank + scatter fused: inv/perm/scs(tanh)
__global__ void brank_k(const ull* __restrict__ k64, const int* __restrict__ habove,
                        const int* __restrict__ isort, const double* __restrict__ z,
                        int* __restrict__ perm, int* __restrict__ inv,
                        double* __restrict__ scs, int n, int kk){
  int i = blockIdx.x*blockDim.x + threadIdx.x;
  if (i >= n) return;
  ull ki = k64[i];
  int b = (int)(ki >> BSHIFT);
  int lo = habove[b];
  int hi = (b > 0) ? habove[b-1] : n;
  int cnt = 0;
  for (int t = lo; t < hi; t++){
    int j = isort[t];
    ull kj = k64[j];
    cnt += ((kj > ki) || (kj == ki && j < i)) ? 1 : 0;
  }
  int r = lo + cnt;
  inv[i] = (r < kk) ? r : -1;
  if (r < kk){ perm[r] = i; scs[r] = tanh(z[i]); }
}

__global__ void reindex_k(const int* __restrict__ src, const int* __restrict__ dst,
                          const int* __restrict__ inv,
                          int* __restrict__ ns, int* __restrict__ nd, int* __restrict__ nmsk, int e){
  int t = blockIdx.x*blockDim.x + threadIdx.x;
  if (t >= e) return;
  int a = inv[src[t]], b = inv[dst[t]];
  int ok = (a >= 0) && (b >= 0);
  ns[t] = ok ? a : 0; nd[t] = ok ? b : 0; nmsk[t] = ok;
}

// edge outputs + batch2 zeros
__global__ void finedge_k(const int* __restrict__ ns, const int* __restrict__ nd,
                          const int* __restrict__ msk, const int* __restrict__ inv,
                          float* __restrict__ osrc, float* __restrict__ odst,
                          float* __restrict__ omsk, float* __restrict__ ob, int e){
  int t = blockIdx.x*blockDim.x + threadIdx.x;
  if (t < KK2) ob[t] = 0.0f;
  if (t >= e) return;
  int a = inv[ns[t]], b = inv[nd[t]];
  int ok = msk[t] && (a >= 0) && (b >= 0);
  osrc[t] = (float)(ok ? a : 0);
  odst[t] = (float)(ok ? b : 0);
  omsk[t] = ok ? 1.0f : 0.0f;
}

extern "C" void kernel_launch(void* const* d_in, const int* in_sizes, int n_in,
                              void* d_out, int out_size, void* d_ws, size_t ws_size,
                              hipStream_t stream){
  (void)in_sizes; (void)n_in; (void)out_size; (void)ws_size;
  const float* x   = (const float*)d_in[0];
  const int*   ei  = (const int*)d_in[1];
  const float* W1  = (const float*)d_in[3];
  const float* as1 = (const float*)d_in[4];
  const float* ad1 = (const float*)d_in[5];
  const float* b1  = (const float*)d_in[6];
  const float* p1  = (const float*)d_in[7];
  const float* W2  = (const float*)d_in[8];
  const float* as2 = (const float*)d_in[9];
  const float* ad2 = (const float*)d_in[10];
  const float* b2  = (const float*)d_in[11];
  const float* p2  = (const float*)d_in[12];
  const int* src0 = ei;
  const int* dst0 = ei + EE;

  char* cur_ = (char*)d_ws;
  auto take = [&](size_t bytes)->void*{ void* p = (void*)cur_; cur_ += (bytes + 255) & ~(size_t)255; return p; };
  double* Xagg = (double*)take((size_t)12500*1024*8);   // 102.4 MB; front 1MB aliases hist in pooling
  double* Xi   = (double*)take((size_t)KK1*256*8);
  double* als  = (double*)take((size_t)NN1*4*8);
  double* ald  = (double*)take((size_t)NN1*4*8);        // aliased by habove
  ull*    menc = (ull*)   take((size_t)NN1*4*8);        // aliased by bcur
  double* wse  = (double*)take((size_t)NN1*4*8);
  double* hp   = (double*)take((size_t)NN1*4*8);
  double* wed  = (double*)take((size_t)EE*4*8);
  double* sco  = (double*)take((size_t)NN1*8);
  double* scs  = (double*)take((size_t)KK1*8);
  double* nrm  = (double*)take(256);
  double* Q    = (double*)take((size_t)3072*8);
  ull*    k64  = (ull*)   take((size_t)NN1*8);
  int* isort= (int*)take((size_t)NN1*4);
  int* prm  = (int*)take((size_t)KK1*4);
  int* inv  = (int*)take((size_t)NN1*4);
  int* deg  = (int*)take((size_t)(NN1+1)*4);
  int* rwp  = (int*)take((size_t)(NN1+1)*4);
  int* cursr= (int*)take((size_t)NN1*4);
  int* csr  = (int*)take((size_t)EE*4);
  int* ns   = (int*)take((size_t)EE*4);
  int* nd   = (int*)take((size_t)EE*4);
  int* mk2  = (int*)take((size_t)EE*4);
  int* btot = (int*)take((size_t)1024*4);

  int* hist   = (int*)Xagg;     // dead during pooling phases
  int* habove = (int*)ald;      // ald dead after nodew
  int* bcur   = (int*)menc;     // menc slot is pure scratch

  float* out = (float*)d_out;
  float* o_x = out;
  float* o_s = out + (size_t)KK2*256;
  float* o_d = o_s + EE;
  float* o_m = o_d + EE;
  float* o_b = o_m + EE;

  // ---------------- stage 1 ----------------
  prepq_k<<<257,256,0,stream>>>(W1, as1, ad1, p1, b1, Q, nrm);
  matvec_k<float><<<CDIV(NN1,64),256,0,stream>>>(x, Q, als, ald, hp, deg, NN1);
  deg_k<<<CDIV(EE,256),256,0,stream>>>(dst0, nullptr, deg, EE);
  scanA_k<<<CDIV(NN1,256),256,0,stream>>>(deg, btot, NN1);
  scanB_k<<<1,1024,0,stream>>>(btot, CDIV(NN1,256));
  scanC_rowptr_k<<<CDIV(NN1,256),256,0,stream>>>(deg, btot, rwp, cursr, NN1);
  place_k<<<CDIV(EE,256),256,0,stream>>>(dst0, nullptr, src0, rwp, cursr, csr, hist, bcur, EE);
  nodew_k<<<CDIV(NN1*4,256),256,0,stream>>>(als, ald, hp, csr, rwp, nrm, wse, wed, sco, NN1);

  // pool 1
  keyhist_k<<<CDIV(NN1,256),256,0,stream>>>(sco, k64, hist, NN1);
  scanA_k<<<NB/256,256,0,stream>>>(hist, btot, NB);
  scanB_k<<<1,1024,0,stream>>>(btot, NB/256);
  scanC_above_k<<<NB/256,256,0,stream>>>(hist, btot, habove, NN1, NB);
  bplace_k<<<CDIV(NN1,256),256,0,stream>>>(k64, habove, bcur, isort, NN1);
  brank_k<<<CDIV(NN1,256),256,0,stream>>>(k64, habove, isort, sco, prm, inv, scs, NN1, KK1);

  // gated features: two chunks of 12500 kept nodes
  aggx4_k<float><<<12500,256,0,stream>>>(x, prm, rwp, csr, wed, wse, Xagg);
  gemmE_k<double><<<dim3(CDIV(12500,32),4),256,0,stream>>>(Xagg, W1, b1, scs, Xi, 12500);
  aggx4_k<float><<<12500,256,0,stream>>>(x, prm+12500, rwp, csr, wed, wse, Xagg);
  gemmE_k<double><<<dim3(CDIV(12500,32),4),256,0,stream>>>(Xagg, W1, b1, scs+12500,
                                                           Xi+(size_t)12500*256, 12500);
  reindex_k<<<CDIV(EE,256),256,0,stream>>>(src0, dst0, inv, ns, nd, mk2, EE);

  // ---------------- stage 2 ----------------
  prepq_k<<<257,256,0,stream>>>(W2, as2, ad2, p2, b2, Q, nrm);
  matvec_k<double><<<CDIV(KK1,64),256,0,stream>>>(Xi, Q, als, ald, hp, deg, KK1);
  deg_k<<<CDIV(EE,256),256,0,stream>>>(nd, mk2, deg, EE);
  scanA_k<<<CDIV(KK1,256),256,0,stream>>>(deg, btot, KK1);
  scanB_k<<<1,1024,0,stream>>>(btot, CDIV(KK1,256));
  scanC_rowptr_k<<<CDIV(KK1,256),256,0,stream>>>(deg, btot, rwp, cursr, KK1);
  place_k<<<CDIV(EE,256),256,0,stream>>>(nd, mk2, ns, rwp, cursr, csr, hist, bcur, EE);
  nodew_k<<<CDIV(KK1*4,256),256,0,stream>>>(als, ald, hp, csr, rwp, nrm, wse, wed, sco, KK1);

  // pool 2 + outputs
  keyhist_k<<<CDIV(KK1,256),256,0,stream>>>(sco, k64, hist, KK1);
  scanA_k<<<NB/256,256,0,stream>>>(hist, btot, NB);
  scanB_k<<<1,1024,0,stream>>>(btot, NB/256);
  scanC_above_k<<<NB/256,256,0,stream>>>(hist, btot, habove, KK1, NB);
  bplace_k<<<CDIV(KK1,256),256,0,stream>>>(k64, habove, bcur, isort, KK1);
  brank_k<<<CDIV(KK1,256),256,0,stream>>>(k64, habove, isort, sco, prm, inv, scs, KK1, KK2);

  aggx4_k<double><<<12500,256,0,stream>>>(Xi, prm, rwp, csr, wed, wse, Xagg);
  gemmE_k<float><<<dim3(CDIV(12500,32),4),256,0,stream>>>(Xagg, W2, b2, scs, o_x, 12500);
  finedge_k<<<CDIV(EE,256),256,0,stream>>>(ns, nd, mk2, inv, o_s, o_d, o_m, o_b, EE);
}

// Round 12
// 756.786 us; speedup vs baseline: 1.0713x; 1.0713x over previous
//
#include <hip/hip_runtime.h>
#include <math.h>

typedef unsigned long long ull;

#define NN1 50000
#define EE  600000
#define KK1 25000
#define KK2 12500

#define NB (1<<18)      // rank buckets
#define BSHIFT 46       // 64-18

#define CDIV(a,b) (((a)+(b)-1)/(b))

__device__ __forceinline__ ull encd(double d){
  ull u = (ull)__double_as_longlong(d);
  return (u & 0x8000000000000000ULL) ? ~u : (u | 0x8000000000000000ULL);
}
__device__ __forceinline__ double lrelu(double z){ return z > 0.0 ? z : 0.2*z; }

// ---------------- Q = [W.a_src | W.a_dst | W.p_heads] : [256][12] f64 ; block 256 = pnorm ----
__global__ void prepq_k(const float* __restrict__ W, const float* __restrict__ as,
                        const float* __restrict__ ad, const float* __restrict__ p,
                        const float* __restrict__ bias, double* __restrict__ Q,
                        double* __restrict__ nrmbp){
  int tid = threadIdx.x;
  if (blockIdx.x == 256){
    __shared__ double ws_[8];
    double pv = (double)p[tid];
    double v = pv*pv;
    double w = (double)bias[tid]*pv;
    for (int off=32; off; off>>=1){ v += __shfl_down(v, off); w += __shfl_down(w, off); }
    if ((tid&63)==0){ ws_[tid>>6] = v; ws_[4+(tid>>6)] = w; }
    __syncthreads();
    if (tid == 0){
      nrmbp[0] = sqrt(ws_[0]+ws_[1]+ws_[2]+ws_[3]);
      nrmbp[1] = ws_[4]+ws_[5]+ws_[6]+ws_[7];
    }
    return;
  }
  int k = blockIdx.x; int head = tid>>6; int lane = tid&63;
  double w = (double)W[k*256 + tid];
  double vs = w*(double)as[tid], vd = w*(double)ad[tid], vp = w*(double)p[tid];
  for (int off=32; off; off>>=1){
    vs += __shfl_down(vs,off); vd += __shfl_down(vd,off); vp += __shfl_down(vp,off);
  }
  if (lane==0){ Q[k*12+head]=vs; Q[k*12+4+head]=vd; Q[k*12+8+head]=vp; }
}

// ---------------- matvec: als/ald/hp = A[n,256] @ Q[256,12], f64 ; zeroes deg ----------------
template<typename TA>
__global__ __launch_bounds__(256) void matvec_k(const TA* __restrict__ A, const double* __restrict__ Q,
                                                double* __restrict__ als, double* __restrict__ ald,
                                                double* __restrict__ hp, int* __restrict__ deg, int n){
  __shared__ double P[4][64][13];
  int tid = threadIdx.x;
  int w = tid >> 6, l = tid & 63;
  int base = blockIdx.x*64;
  int r = base + l;
  double acc[12];
  #pragma unroll
  for (int j=0;j<12;j++) acc[j] = 0.0;
  if (r < n){
    const TA*    rowp = A + (size_t)r*256 + w*64;
    const double* qp  = Q + (size_t)w*64*12;
    if constexpr (sizeof(TA)==4){
      #pragma unroll 4
      for (int i=0;i<16;i++){
        float4 v = *reinterpret_cast<const float4*>(rowp + i*4);
        double e0=(double)v.x, e1=(double)v.y, e2=(double)v.z, e3=(double)v.w;
        #pragma unroll
        for (int j=0;j<12;j++) acc[j] = fma(e0, qp[(i*4+0)*12+j], acc[j]);
        #pragma unroll
        for (int j=0;j<12;j++) acc[j] = fma(e1, qp[(i*4+1)*12+j], acc[j]);
        #pragma unroll
        for (int j=0;j<12;j++) acc[j] = fma(e2, qp[(i*4+2)*12+j], acc[j]);
        #pragma unroll
        for (int j=0;j<12;j++) acc[j] = fma(e3, qp[(i*4+3)*12+j], acc[j]);
      }
    } else {
      #pragma unroll 4
      for (int i=0;i<32;i++){
        double2 v = *reinterpret_cast<const double2*>(rowp + i*2);
        #pragma unroll
        for (int j=0;j<12;j++) acc[j] = fma(v.x, qp[(i*2+0)*12+j], acc[j]);
        #pragma unroll
        for (int j=0;j<12;j++) acc[j] = fma(v.y, qp[(i*2+1)*12+j], acc[j]);
      }
    }
  }
  #pragma unroll
  for (int j=0;j<12;j++) P[w][l][j] = acc[j];
  __syncthreads();
  if (tid < 64){
    int rr = base + tid;
    if (rr < n){
      double s[12];
      #pragma unroll
      for (int j=0;j<12;j++)
        s[j] = ((P[0][tid][j] + P[1][tid][j]) + P[2][tid][j]) + P[3][tid][j];
      #pragma unroll
      for (int h=0;h<4;h++){
        als[rr*4+h] = s[h];
        ald[rr*4+h] = s[4+h];
        hp [rr*4+h] = s[8+h];
      }
      deg[rr] = 0;
    }
  }
}

__global__ void deg_k(const int* __restrict__ dst, const int* __restrict__ msk,
                      int* __restrict__ deg, int e){
  int t = blockIdx.x*blockDim.x + threadIdx.x;
  if (t >= e) return;
  if (msk && !msk[t]) return;
  atomicAdd(&deg[dst[t]], 1);
}

// ---------------- hierarchical scan (blocks of 256) ----------------
__global__ __launch_bounds__(256) void scanA_k(int* __restrict__ a, int* __restrict__ btot, int n){
  __shared__ int s[256];
  int g = blockIdx.x*256 + threadIdx.x;
  s[threadIdx.x] = (g < n) ? a[g] : 0;
  __syncthreads();
  for (int off=1; off<256; off<<=1){
    int t = (threadIdx.x >= off) ? s[threadIdx.x-off] : 0;
    __syncthreads();
    s[threadIdx.x] += t;
    __syncthreads();
  }
  if (g < n) a[g] = s[threadIdx.x];
  if (threadIdx.x == 255) btot[blockIdx.x] = s[255];
}

__global__ __launch_bounds__(1024) void scanB_k(int* __restrict__ btot, int nb){
  __shared__ int s[1024];
  int t = threadIdx.x;
  s[t] = (t < nb) ? btot[t] : 0;
  __syncthreads();
  for (int off=1; off<1024; off<<=1){
    int v = (t >= off) ? s[t-off] : 0;
    __syncthreads();
    s[t] += v;
    __syncthreads();
  }
  if (t < nb) btot[t] = s[t];
}

__global__ void scanC_rowptr_k(const int* __restrict__ a, const int* __restrict__ btot,
                               int* __restrict__ rowptr, int* __restrict__ cursor, int n){
  int g = blockIdx.x*blockDim.x + threadIdx.x;
  if (g >= n) return;
  int B = g >> 8;
  int off = (B > 0) ? btot[B-1] : 0;
  rowptr[g+1] = a[g] + off;
  cursor[g] = 0;
  if (g == 0) rowptr[0] = 0;
}

__global__ void scanC_above_k(const int* __restrict__ a, const int* __restrict__ btot,
                              int* __restrict__ habove, int nelems, int nbins){
  int g = blockIdx.x*blockDim.x + threadIdx.x;
  if (g >= nbins) return;
  int B = g >> 8;
  int off = (B > 0) ? btot[B-1] : 0;
  habove[g] = nelems - (a[g] + off);
}

// place src into csr slots of dst; also zero hist/bcur (used later in pooling)
__global__ void place_k(const int* __restrict__ dst, const int* __restrict__ msk,
                        const int* __restrict__ src, const int* __restrict__ rowptr,
                        int* __restrict__ cursor, int* __restrict__ csr,
                        int* __restrict__ hist, int* __restrict__ bcur, int e){
  int t = blockIdx.x*blockDim.x + threadIdx.x;
  if (t < NB){ hist[t] = 0; bcur[t] = 0; }
  if (t >= e) return;
  if (msk && !msk[t]) return;
  int d = dst[t];
  int slot = atomicAdd(&cursor[d], 1);
  csr[rowptr[d] + slot] = src[t];
}

// ---------------- per-node: segment max, softmax weights, pooling score ----------------
__global__ void nodew_k(const double* __restrict__ als, const double* __restrict__ ald,
                        const double* __restrict__ hp, const int* __restrict__ csr,
                        const int* __restrict__ rowptr, const double* __restrict__ nrmbp,
                        double* __restrict__ wse, double* __restrict__ wed,
                        double* __restrict__ z, int n){
  int g = blockIdx.x*blockDim.x + threadIdx.x;
  int i = g>>2, h = g&3;
  if (i >= n) return;
  double aldv = ald[g];
  double selfev = lrelu(als[g] + aldv);
  int b = rowptr[i], e = rowptr[i+1];
  double m = selfev;
  for (int t=b; t<e; t++){
    int s = csr[t];
    double ev = lrelu(als[s*4+h] + aldv);
    m = fmax(m, ev);
  }
  double ws = exp(selfev - m);
  wse[g] = ws;
  double acc = ws * hp[g];
  double den = ws;
  for (int t=b; t<e; t++){
    int s = csr[t];
    double ev = lrelu(als[s*4+h] + aldv);
    double w = exp(ev - m);
    wed[(long)t*4+h] = w;
    acc = fma(w, hp[(long)s*4+h], acc);
    den += w;
  }
  double part = acc/den;
  part += __shfl_xor(part, 1);
  part += __shfl_xor(part, 2);
  if (h == 0) z[i] = (part + nrmbp[1]) / nrmbp[0];
}

// ---------------- per-head aggregation of raw features for kept nodes ----------------
template<typename TA>
__global__ void aggx4_k(const TA* __restrict__ X, const int* __restrict__ prm,
                        const int* __restrict__ rowptr, const int* __restrict__ csr,
                        const double* __restrict__ wed, const double* __restrict__ wse,
                        double* __restrict__ Xagg){
  int r = blockIdx.x, k = threadIdx.x;
  int i = prm[r];
  double w0 = wse[i*4+0], w1 = wse[i*4+1], w2 = wse[i*4+2], w3 = wse[i*4+3];
  double xv = (double)X[(long)i*256 + k];
  double a0=w0*xv, a1=w1*xv, a2=w2*xv, a3=w3*xv;
  double d0=w0, d1=w1, d2=w2, d3=w3;
  int b = rowptr[i], e = rowptr[i+1];
  for (int t=b; t<e; t++){
    int s = csr[t];
    double sv = (double)X[(long)s*256 + k];
    double e0=wed[(long)t*4+0], e1=wed[(long)t*4+1];
    double e2=wed[(long)t*4+2], e3=wed[(long)t*4+3];
    a0=fma(e0,sv,a0); a1=fma(e1,sv,a1); a2=fma(e2,sv,a2); a3=fma(e3,sv,a3);
    d0+=e0; d1+=e1; d2+=e2; d3+=e3;
  }
  long base = (long)r*1024 + k;
  Xagg[base      ] = a0/d0;
  Xagg[base + 256] = a1/d1;
  Xagg[base + 512] = a2/d2;
  Xagg[base + 768] = a3/d3;
}

// ---------------- f64 GEMM + epilogue (round-10 geometry): Xi = relu(scs*(Xagg@W+b)) ----------
__global__ __launch_bounds__(256) void gemmE_k(const double* __restrict__ A,
                                               const float* __restrict__ W,
                                               const float* __restrict__ bias,
                                               const double* __restrict__ scs,
                                               double* __restrict__ Out, int n){
  __shared__ double As[64][34];
  __shared__ double Bs[32][68];
  int tid = threadIdx.x;
  int r0 = blockIdx.x*64; int head = blockIdx.y; int c0 = head*64;
  int ty = tid>>4, tx = tid&15;
  double acc[4][4] = {};
  for (int k0=0; k0<256; k0+=32){
    int kA = tid&31, rA = tid>>5;
    #pragma unroll
    for (int i=0;i<8;i++){
      int rr = rA + i*8; int gr = r0+rr;
      As[rr][kA] = (gr<n) ? A[(long)gr*1024 + head*256 + k0 + kA] : 0.0;
    }
    int cB = tid&63, kB = tid>>6;
    #pragma unroll
    for (int i=0;i<8;i++){
      int kk = kB + i*4;
      Bs[kk][cB] = (double)W[(k0+kk)*256 + c0 + cB];
    }
    __syncthreads();
    #pragma unroll 4
    for (int k=0;k<32;k+=2){
      double2 a2[4];
      double blo[4], bhi[4];
      #pragma unroll
      for (int i=0;i<4;i++) a2[i] = *reinterpret_cast<const double2*>(&As[ty*4+i][k]);
      #pragma unroll
      for (int j=0;j<4;j++){ blo[j] = Bs[k][tx+16*j]; bhi[j] = Bs[k+1][tx+16*j]; }
      #pragma unroll
      for (int i=0;i<4;i++)
        #pragma unroll
        for (int j=0;j<4;j++) acc[i][j] = fma(a2[i].x, blo[j], acc[i][j]);
      #pragma unroll
      for (int i=0;i<4;i++)
        #pragma unroll
        for (int j=0;j<4;j++) acc[i][j] = fma(a2[i].y, bhi[j], acc[i][j]);
    }
    __syncthreads();
  }
  #pragma unroll
  for (int i=0;i<4;i++){
    int gr = r0 + ty*4 + i;
    if (gr < n){
      double s = scs[gr];
      #pragma unroll
      for (int j=0;j<4;j++){
        int c = c0 + tx + 16*j;
        double v = (acc[i][j] + (double)bias[c]) * s;
        Out[(long)gr*256 + c] = v > 0.0 ? v : 0.0;
      }
    }
  }
}

// ---------------- f32 GEMM + epilogue for the FINAL output (no downstream consumers) --------
__global__ __launch_bounds__(256) void gemmF_k(const double* __restrict__ A,
                                               const float* __restrict__ W,
                                               const float* __restrict__ bias,
                                               const double* __restrict__ scs,
                                               float* __restrict__ Out, int n){
  __shared__ float As[64][36];   // 36*4=144=9*16 -> aligned, light aliasing only
  __shared__ float Bs[32][68];
  int tid = threadIdx.x;
  int r0 = blockIdx.x*64; int head = blockIdx.y; int c0 = head*64;
  int ty = tid>>4, tx = tid&15;
  float acc[4][4] = {};
  for (int k0=0; k0<256; k0+=32){
    int kA = tid&31, rA = tid>>5;
    #pragma unroll
    for (int i=0;i<8;i++){
      int rr = rA + i*8; int gr = r0+rr;
      As[rr][kA] = (gr<n) ? (float)A[(long)gr*1024 + head*256 + k0 + kA] : 0.0f;
    }
    int cB = tid&63, kB = tid>>6;
    #pragma unroll
    for (int i=0;i<8;i++){
      int kk = kB + i*4;
      Bs[kk][cB] = W[(k0+kk)*256 + c0 + cB];
    }
    __syncthreads();
    #pragma unroll 4
    for (int k=0;k<32;k+=2){
      float2 a2[4];
      float blo[4], bhi[4];
      #pragma unroll
      for (int i=0;i<4;i++) a2[i] = *reinterpret_cast<const float2*>(&As[ty*4+i][k]);
      #pragma unroll
      for (int j=0;j<4;j++){ blo[j] = Bs[k][tx+16*j]; bhi[j] = Bs[k+1][tx+16*j]; }
      #pragma unroll
      for (int i=0;i<4;i++)
        #pragma unroll
        for (int j=0;j<4;j++) acc[i][j] = fmaf(a2[i].x, blo[j], acc[i][j]);
      #pragma unroll
      for (int i=0;i<4;i++)
        #pragma unroll
        for (int j=0;j<4;j++) acc[i][j] = fmaf(a2[i].y, bhi[j], acc[i][j]);
    }
    __syncthreads();
  }
  #pragma unroll
  for (int i=0;i<4;i++){
    int gr = r0 + ty*4 + i;
    if (gr < n){
      float s = (float)scs[gr];
      #pragma unroll
      for (int j=0;j<4;j++){
        int c = c0 + tx + 16*j;
        float v = (acc[i][j] + bias[c]) * s;
        Out[(long)gr*256 + c] = v > 0.0f ? v : 0.0f;
      }
    }
  }
}

// ---------------- bucket-based exact ranking ----------------
__global__ void keyhist_k(const double* __restrict__ z, ull* __restrict__ k64,
                          int* __restrict__ hist, int n){
  int i = blockIdx.x*blockDim.x + threadIdx.x;
  if (i >= n) return;
  ull e = encd(z[i]);
  k64[i] = e;
  atomicAdd(&hist[(int)(e >> BSHIFT)], 1);
}

__global__ void bplace_k(const ull* __restrict__ k64, const int* __restrict__ habove,
                         int* __restrict__ cur, int* __restrict__ isort, int n){
  int i = blockIdx.x*blockDim.x + threadIdx.x;
  if (i >= n) return;
  int b = (int)(k64[i] >> BSHIFT);
  int slot = atomicAdd(&cur[b], 1);
  isort[habove[b] + slot] = i;
}

// rank + scatter fused: inv/perm/scs(tanh)
__global__ void brank_k(const ull* __restrict__ k64, const int* __restrict__ habove,
                        const int* __restrict__ isort, const double* __restrict__ z,
                        int* __restrict__ perm, int* __restrict__ inv,
                        double* __restrict__ scs, int n, int kk){
  int i = blockIdx.x*blockDim.x + threadIdx.x;
  if (i >= n) return;
  ull ki = k64[i];
  int b = (int)(ki >> BSHIFT);
  int lo = habove[b];
  int hi = (b > 0) ? habove[b-1] : n;
  int cnt = 0;
  for (int t = lo; t < hi; t++){
    int j = isort[t];
    ull kj = k64[j];
    cnt += ((kj > ki) || (kj == ki && j < i)) ? 1 : 0;
  }
  int r = lo + cnt;
  inv[i] = (r < kk) ? r : -1;
  if (r < kk){ perm[r] = i; scs[r] = tanh(z[i]); }
}

__global__ void reindex_k(const int* __restrict__ src, const int* __restrict__ dst,
                          const int* __restrict__ inv,
                          int* __restrict__ ns, int* __restrict__ nd, int* __restrict__ nmsk, int e){
  int t = blockIdx.x*blockDim.x + threadIdx.x;
  if (t >= e) return;
  int a = inv[src[t]], b = inv[dst[t]];
  int ok = (a >= 0) && (b >= 0);
  ns[t] = ok ? a : 0; nd[t] = ok ? b : 0; nmsk[t] = ok;
}

// edge outputs + batch2 zeros
__global__ void finedge_k(const int* __restrict__ ns, const int* __restrict__ nd,
                          const int* __restrict__ msk, const int* __restrict__ inv,
                          float* __restrict__ osrc, float* __restrict__ odst,
                          float* __restrict__ omsk, float* __restrict__ ob, int e){
  int t = blockIdx.x*blockDim.x + threadIdx.x;
  if (t < KK2) ob[t] = 0.0f;
  if (t >= e) return;
  int a = inv[ns[t]], b = inv[nd[t]];
  int ok = msk[t] && (a >= 0) && (b >= 0);
  osrc[t] = (float)(ok ? a : 0);
  odst[t] = (float)(ok ? b : 0);
  omsk[t] = ok ? 1.0f : 0.0f;
}

extern "C" void kernel_launch(void* const* d_in, const int* in_sizes, int n_in,
                              void* d_out, int out_size, void* d_ws, size_t ws_size,
                              hipStream_t stream){
  (void)in_sizes; (void)n_in; (void)out_size; (void)ws_size;
  const float* x   = (const float*)d_in[0];
  const int*   ei  = (const int*)d_in[1];
  const float* W1  = (const float*)d_in[3];
  const float* as1 = (const float*)d_in[4];
  const float* ad1 = (const float*)d_in[5];
  const float* b1  = (const float*)d_in[6];
  const float* p1  = (const float*)d_in[7];
  const float* W2  = (const float*)d_in[8];
  const float* as2 = (const float*)d_in[9];
  const float* ad2 = (const float*)d_in[10];
  const float* b2  = (const float*)d_in[11];
  const float* p2  = (const float*)d_in[12];
  const int* src0 = ei;
  const int* dst0 = ei + EE;

  char* cur_ = (char*)d_ws;
  auto take = [&](size_t bytes)->void*{ void* p = (void*)cur_; cur_ += (bytes + 255) & ~(size_t)255; return p; };
  double* Xagg = (double*)take((size_t)12500*1024*8);   // 102.4 MB; front 1MB aliases hist in pooling
  double* Xi   = (double*)take((size_t)KK1*256*8);
  double* als  = (double*)take((size_t)NN1*4*8);
  double* ald  = (double*)take((size_t)NN1*4*8);        // aliased by habove
  ull*    menc = (ull*)   take((size_t)NN1*4*8);        // aliased by bcur
  double* wse  = (double*)take((size_t)NN1*4*8);
  double* hp   = (double*)take((size_t)NN1*4*8);
  double* wed  = (double*)take((size_t)EE*4*8);
  double* sco  = (double*)take((size_t)NN1*8);
  double* scs  = (double*)take((size_t)KK1*8);
  double* nrm  = (double*)take(256);
  double* Q    = (double*)take((size_t)3072*8);
  ull*    k64  = (ull*)   take((size_t)NN1*8);
  int* isort= (int*)take((size_t)NN1*4);
  int* prm  = (int*)take((size_t)KK1*4);
  int* inv  = (int*)take((size_t)NN1*4);
  int* deg  = (int*)take((size_t)(NN1+1)*4);
  int* rwp  = (int*)take((size_t)(NN1+1)*4);
  int* cursr= (int*)take((size_t)NN1*4);
  int* csr  = (int*)take((size_t)EE*4);
  int* ns   = (int*)take((size_t)EE*4);
  int* nd   = (int*)take((size_t)EE*4);
  int* mk2  = (int*)take((size_t)EE*4);
  int* btot = (int*)take((size_t)1024*4);

  int* hist   = (int*)Xagg;     // dead during pooling phases
  int* habove = (int*)ald;      // ald dead after nodew
  int* bcur   = (int*)menc;     // menc slot is pure scratch

  float* out = (float*)d_out;
  float* o_x = out;
  float* o_s = out + (size_t)KK2*256;
  float* o_d = o_s + EE;
  float* o_m = o_d + EE;
  float* o_b = o_m + EE;

  // ---------------- stage 1 ----------------
  prepq_k<<<257,256,0,stream>>>(W1, as1, ad1, p1, b1, Q, nrm);
  matvec_k<float><<<CDIV(NN1,64),256,0,stream>>>(x, Q, als, ald, hp, deg, NN1);
  deg_k<<<CDIV(EE,256),256,0,stream>>>(dst0, nullptr, deg, EE);
  scanA_k<<<CDIV(NN1,256),256,0,stream>>>(deg, btot, NN1);
  scanB_k<<<1,1024,0,stream>>>(btot, CDIV(NN1,256));
  scanC_rowptr_k<<<CDIV(NN1,256),256,0,stream>>>(deg, btot, rwp, cursr, NN1);
  place_k<<<CDIV(EE,256),256,0,stream>>>(dst0, nullptr, src0, rwp, cursr, csr, hist, bcur, EE);
  nodew_k<<<CDIV(NN1*4,256),256,0,stream>>>(als, ald, hp, csr, rwp, nrm, wse, wed, sco, NN1);

  // pool 1
  keyhist_k<<<CDIV(NN1,256),256,0,stream>>>(sco, k64, hist, NN1);
  scanA_k<<<NB/256,256,0,stream>>>(hist, btot, NB);
  scanB_k<<<1,1024,0,stream>>>(btot, NB/256);
  scanC_above_k<<<NB/256,256,0,stream>>>(hist, btot, habove, NN1, NB);
  bplace_k<<<CDIV(NN1,256),256,0,stream>>>(k64, habove, bcur, isort, NN1);
  brank_k<<<CDIV(NN1,256),256,0,stream>>>(k64, habove, isort, sco, prm, inv, scs, NN1, KK1);

  // gated features: two chunks of 12500 kept nodes
  aggx4_k<float><<<12500,256,0,stream>>>(x, prm, rwp, csr, wed, wse, Xagg);
  gemmE_k<<<dim3(CDIV(12500,64),4),256,0,stream>>>(Xagg, W1, b1, scs, Xi, 12500);
  aggx4_k<float><<<12500,256,0,stream>>>(x, prm+12500, rwp, csr, wed, wse, Xagg);
  gemmE_k<<<dim3(CDIV(12500,64),4),256,0,stream>>>(Xagg, W1, b1, scs+12500,
                                                   Xi+(size_t)12500*256, 12500);
  reindex_k<<<CDIV(EE,256),256,0,stream>>>(src0, dst0, inv, ns, nd, mk2, EE);

  // ---------------- stage 2 ----------------
  prepq_k<<<257,256,0,stream>>>(W2, as2, ad2, p2, b2, Q, nrm);
  matvec_k<double><<<CDIV(KK1,64),256,0,stream>>>(Xi, Q, als, ald, hp, deg, KK1);
  deg_k<<<CDIV(EE,256),256,0,stream>>>(nd, mk2, deg, EE);
  scanA_k<<<CDIV(KK1,256),256,0,stream>>>(deg, btot, KK1);
  scanB_k<<<1,1024,0,stream>>>(btot, CDIV(KK1,256));
  scanC_rowptr_k<<<CDIV(KK1,256),256,0,stream>>>(deg, btot, rwp, cursr, KK1);
  place_k<<<CDIV(EE,256),256,0,stream>>>(nd, mk2, ns, rwp, cursr, csr, hist, bcur, EE);
  nodew_k<<<CDIV(KK1*4,256),256,0,stream>>>(als, ald, hp, csr, rwp, nrm, wse, wed, sco, KK1);

  // pool 2 + outputs
  keyhist_k<<<CDIV(KK1,256),256,0,stream>>>(sco, k64, hist, KK1);
  scanA_k<<<NB/256,256,0,stream>>>(hist, btot, NB);
  scanB_k<<<1,1024,0,stream>>>(btot, NB/256);
  scanC_above_k<<<NB/256,256,0,stream>>>(hist, btot, habove, KK1, NB);
  bplace_k<<<CDIV(KK1,256),256,0,stream>>>(k64, habove, bcur, isort, KK1);
  brank_k<<<CDIV(KK1,256),256,0,stream>>>(k64, habove, isort, sco, prm, inv, scs, KK1, KK2);

  aggx4_k<double><<<12500,256,0,stream>>>(Xi, prm, rwp, csr, wed, wse, Xagg);
  gemmF_k<<<dim3(CDIV(12500,64),4),256,0,stream>>>(Xagg, W2, b2, scs, o_x, 12500);
  finedge_k<<<CDIV(EE,256),256,0,stream>>>(ns, nd, mk2, inv, o_s, o_d, o_m, o_b, EE);
}